// Round 7
// baseline (328.803 us; speedup 1.0000x reference)
//
#include <hip/hip_runtime.h>

typedef short bf16x8 __attribute__((ext_vector_type(8)));
typedef float f32x4 __attribute__((ext_vector_type(4)));
typedef unsigned short u16;

#define S_LEN 4096
#define D_DIM 256
#define NROW  16384   // B*S

__device__ __forceinline__ u16 f2bf(float f) {
    union { float f; unsigned u; } v; v.f = f;
    unsigned r = v.u + 0x7FFFu + ((v.u >> 16) & 1u);
    return (u16)(r >> 16);
}
__device__ __forceinline__ float bf2f(u16 h) {
    union { unsigned u; float f; } v; v.u = ((unsigned)h) << 16; return v.f;
}

// Fragment-linear layouts (bf16):
//  Q/K/W: row-tile t (16 rows), kk (32-depth chunk): frag = t*4096 + kk*512,
//         elem(row_local, col) at ((col>>3)&3)*128 + row_local*8 + (col&7).
//  V^T:   panel p = b*64+kt (64 keys x 256 d): frag(dt,kk2) = p*16384+(dt*2+kk2)*512.
//  E^T:   [k][q] B-operand frags: frag(b, kc32, qt16) at e_base; within:
//         (klocal>>3)*128 + qlocal*8 + (klocal&7).
__device__ __forceinline__ size_t fr_qk(int t, int kk) {
    return (size_t)t * 4096 + kk * 512;
}
__device__ __forceinline__ size_t fr_v(int p, int dt, int kk2) {
    return (size_t)p * 16384 + (dt * 2 + kk2) * 512;
}
__device__ __forceinline__ size_t e_base(int b, int kc, int qt) {
    return ((size_t)(b * 32768 + kc * 256 + qt)) * 512;
}

// async global->LDS, 16B/lane: lane l's 16B from g+l*8(u16) lands at lds+l*16.
__device__ __forceinline__ void gll16(const u16* g, u16* l) {
    __builtin_amdgcn_global_load_lds(
        (const __attribute__((address_space(1))) unsigned int*)g,
        (__attribute__((address_space(3))) unsigned int*)l, 16, 0, 0);
}

// ---------------- Kernel W: W f32 -> bf16 fragments -----------------------
__global__ __launch_bounds__(256) void wconv(
    const float* __restrict__ Wq, const float* __restrict__ Wk,
    const float* __restrict__ Wv, u16* __restrict__ Wf)
{
    int i = blockIdx.x * 256 + threadIdx.x;
    int m = i >> 13;
    int idx = i & 8191;
    int ocol = idx >> 5;
    int d0 = (idx & 31) * 8;
    const float* s = (m == 0 ? Wq : (m == 1 ? Wk : Wv)) + ocol * 256 + d0;
    float4 v0 = *reinterpret_cast<const float4*>(s);
    float4 v1 = *reinterpret_cast<const float4*>(s + 4);
    union { ushort4 h[2]; int4 q; } t;
    t.h[0] = make_ushort4(f2bf(v0.x), f2bf(v0.y), f2bf(v0.z), f2bf(v0.w));
    t.h[1] = make_ushort4(f2bf(v1.x), f2bf(v1.y), f2bf(v1.z), f2bf(v1.w));
    size_t off = (size_t)m * 65536 + fr_qk(ocol >> 4, d0 >> 5)
               + ((d0 >> 3) & 3) * 128 + (ocol & 15) * 8;
    *reinterpret_cast<int4*>(Wf + off) = t.q;
}

// ---------------- Kernel A: QKV projection (32 rows/block) ----------------
__global__ __launch_bounds__(256) void qkv_proj(
    const float* __restrict__ x, const u16* __restrict__ Wf,
    const float* __restrict__ bq, const float* __restrict__ bk,
    const float* __restrict__ bv,
    u16* __restrict__ Qf, u16* __restrict__ Kf, u16* __restrict__ Vf)
{
    __shared__ u16 xs[32][264];
    const int tid = threadIdx.x;
    const int r0 = blockIdx.x * 32;

    #pragma unroll
    for (int i = 0; i < 8; ++i) {
        int c = i * 256 + tid;
        int row = c >> 6, c4 = c & 63;
        float4 v = reinterpret_cast<const float4*>(x + (size_t)(r0 + row) * D_DIM)[c4];
        *reinterpret_cast<ushort4*>(&xs[row][c4 * 4]) =
            make_ushort4(f2bf(v.x), f2bf(v.y), f2bf(v.z), f2bf(v.w));
    }
    __syncthreads();

    const int w = tid >> 6, l = tid & 63, lr = l & 15, lg = l >> 4;
    const int c0 = w * 64;

    bf16x8 a[2][8];
    #pragma unroll
    for (int qs = 0; qs < 2; ++qs)
        #pragma unroll
        for (int kk = 0; kk < 8; ++kk)
            a[qs][kk] = *reinterpret_cast<const bf16x8*>(&xs[qs * 16 + lr][kk * 32 + lg * 8]);

    const float* Bs[3] = {bq, bk, bv};

    #pragma unroll
    for (int m = 0; m < 3; ++m) {
        const u16* Wm = Wf + (size_t)m * 65536;
        f32x4 acc[2][4] = {};
        #pragma unroll
        for (int kk = 0; kk < 8; ++kk) {
            #pragma unroll
            for (int cf = 0; cf < 4; ++cf) {
                bf16x8 wfr = *reinterpret_cast<const bf16x8*>(
                    Wm + fr_qk(w * 4 + cf, kk) + l * 8);
                acc[0][cf] = __builtin_amdgcn_mfma_f32_16x16x32_bf16(a[0][kk], wfr, acc[0][cf], 0, 0, 0);
                acc[1][cf] = __builtin_amdgcn_mfma_f32_16x16x32_bf16(a[1][kk], wfr, acc[1][cf], 0, 0, 0);
            }
        }
        if (m < 2) {
            u16* outp = (m == 0) ? Qf : Kf;
            int t = r0 >> 4;
            #pragma unroll
            for (int qs = 0; qs < 2; ++qs) {
                #pragma unroll
                for (int cf = 0; cf < 4; ++cf) {
                    int col = c0 + cf * 16 + lr;
                    float bias = Bs[m][col];
                    size_t base = fr_qk(t + qs, col >> 5) + ((col >> 3) & 3) * 128 + (col & 7);
                    #pragma unroll
                    for (int r = 0; r < 4; ++r)
                        outp[base + (lg * 4 + r) * 8] = f2bf(acc[qs][cf][r] + bias);
                }
            }
        } else {
            int p  = (r0 >> 12) * 64 + ((r0 & 4095) >> 6);
            int kb = r0 & 63;
            #pragma unroll
            for (int qs = 0; qs < 2; ++qs) {
                #pragma unroll
                for (int cf = 0; cf < 4; ++cf) {
                    int d = c0 + cf * 16 + lr;
                    float bias = bv[d];
                    #pragma unroll
                    for (int r = 0; r < 4; ++r) {
                        int key = kb + qs * 16 + lg * 4 + r;
                        size_t off = fr_v(p, d >> 4, key >> 5)
                                   + ((key >> 3) & 3) * 128 + (d & 15) * 8 + (key & 7);
                        Vf[off] = f2bf(acc[qs][cf][r] + bias);
                    }
                }
            }
        }
    }
}

// ---------------- Kernel B: E^T = exp(S^T/16) + Z partials ----------------
// Block = (batch, 128-key block, q-quarter). K rows persistent in regs
// (swapped mfma(K,Q) -> C rows = k). Writes E^T fragments with coalesced
// ushort4 stores; Z partial per q-quarter written non-atomically.
__global__ __launch_bounds__(256, 2) void score_exp(
    const u16* __restrict__ Qf, const u16* __restrict__ Kf,
    u16* __restrict__ Ef, float* __restrict__ Zp)
{
    __shared__ __align__(16) u16 Qls[2][16384];   // 2 x 32KB q-panels
    const int tid = threadIdx.x, blk = blockIdx.x;
    const int xcd = blk & 7, idx = blk >> 3;
    const int b  = xcd >> 1;                       // batch on 2 XCDs
    const int qs = ((xcd & 1) << 1) | (idx & 1);   // q-quarter
    const int kb = idx >> 1;                       // key-block 0..31
    const int w = tid >> 6, l = tid & 63, lr = l & 15, lg = l >> 4;
    const int k0 = kb * 128;

    bf16x8 kreg[2][8];
    #pragma unroll
    for (int h = 0; h < 2; ++h) {
        const int tk = b * 256 + (k0 >> 4) + w * 2 + h;
        #pragma unroll
        for (int kk = 0; kk < 8; ++kk)
            kreg[h][kk] = *reinterpret_cast<const bf16x8*>(Kf + fr_qk(tk, kk) + l * 8);
    }

    #define STAGE_Q(qi_, nb_) do { \
        const size_t srcb = ((size_t)(b * 256 + qs * 64 + (qi_) * 4)) * 4096; \
        _Pragma("unroll") \
        for (int f_ = 0; f_ < 8; ++f_) \
            gll16(Qf + srcb + (w * 8 + f_) * 512 + l * 8, &Qls[nb_][(w * 8 + f_) * 512]); \
    } while (0)

    STAGE_Q(0, 0);
    __syncthreads();

    float zacc[2][4] = {};
    const float SC = 0.0625f;
    const int kc = kb * 4 + w;                     // this wave's 32-key chunk

    for (int qi = 0; qi < 16; ++qi) {
        const int cur = qi & 1;
        if (qi < 15) STAGE_Q(qi + 1, cur ^ 1);

        f32x4 sacc[2][4] = {};
        #pragma unroll
        for (int kk = 0; kk < 8; ++kk) {
            #pragma unroll
            for (int qf = 0; qf < 4; ++qf) {
                bf16x8 qfr = *reinterpret_cast<const bf16x8*>(
                    &Qls[cur][(qf * 8 + kk) * 512 + l * 8]);
                sacc[0][qf] = __builtin_amdgcn_mfma_f32_16x16x32_bf16(kreg[0][kk], qfr, sacc[0][qf], 0, 0, 0);
                sacc[1][qf] = __builtin_amdgcn_mfma_f32_16x16x32_bf16(kreg[1][kk], qfr, sacc[1][qf], 0, 0, 0);
            }
        }
        // E^T store: k = k0+w*32+h*16+lg*4+r (4 consecutive per lane), q = q0+qf*16+lr
        const int qt0 = qs * 64 + qi * 4;
        #pragma unroll
        for (int h = 0; h < 2; ++h) {
            #pragma unroll
            for (int qf = 0; qf < 4; ++qf) {
                float e0 = __expf(sacc[h][qf][0] * SC);
                float e1 = __expf(sacc[h][qf][1] * SC);
                float e2 = __expf(sacc[h][qf][2] * SC);
                float e3 = __expf(sacc[h][qf][3] * SC);
                zacc[h][0] += e0; zacc[h][1] += e1; zacc[h][2] += e2; zacc[h][3] += e3;
                size_t addr = e_base(b, kc, qt0 + qf)
                            + (size_t)((h * 2 + (lg >> 1)) * 128 + lr * 8 + (lg & 1) * 4);
                *reinterpret_cast<ushort4*>(Ef + addr) =
                    make_ushort4(f2bf(e0), f2bf(e1), f2bf(e2), f2bf(e3));
            }
        }
        __syncthreads();
    }

    #pragma unroll
    for (int h = 0; h < 2; ++h) {
        #pragma unroll
        for (int r = 0; r < 4; ++r) {
            float z = zacc[h][r];
            z += __shfl_xor(z, 1);
            z += __shfl_xor(z, 2);
            z += __shfl_xor(z, 4);
            z += __shfl_xor(z, 8);
            if (lr == 0)
                Zp[qs * NROW + b * S_LEN + k0 + w * 32 + h * 16 + lg * 4 + r] = z;
        }
    }
    #undef STAGE_Q
}

// ---------------- Kernel Z: rZ = 1 / sum(Zp) (fixed order, bit-exact) -----
__global__ __launch_bounds__(256) void zrecip(
    const float* __restrict__ Zp, float* __restrict__ rZ)
{
    int i = blockIdx.x * 256 + threadIdx.x;
    rZ[i] = 1.0f / (((Zp[i] + Zp[NROW + i]) + Zp[2 * NROW + i]) + Zp[3 * NROW + i]);
}

// ---------------- Kernel V: V' = rZ[k] * V (in place on Vf) ---------------
__global__ __launch_bounds__(256) void vscale(
    u16* __restrict__ Vf, const float* __restrict__ rZ)
{
    int i = blockIdx.x * 256 + threadIdx.x;       // 524288 threads, 8 u16 each
    int frag = i >> 6, l8 = i & 63;
    int p = frag >> 5, sub = frag & 31, kk2 = sub & 1;
    int b = p >> 6, kt = p & 63;
    int kbase = b * S_LEN + kt * 64 + kk2 * 32 + (l8 >> 4) * 8;
    float4 rz0 = *reinterpret_cast<const float4*>(&rZ[kbase]);
    float4 rz1 = *reinterpret_cast<const float4*>(&rZ[kbase + 4]);
    ushort4* vp = reinterpret_cast<ushort4*>(Vf + (size_t)i * 8);
    ushort4 a = vp[0], c = vp[1];
    vp[0] = make_ushort4(f2bf(bf2f(a.x) * rz0.x), f2bf(bf2f(a.y) * rz0.y),
                         f2bf(bf2f(a.z) * rz0.z), f2bf(bf2f(a.w) * rz0.w));
    vp[1] = make_ushort4(f2bf(bf2f(c.x) * rz1.x), f2bf(bf2f(c.y) * rz1.y),
                         f2bf(bf2f(c.z) * rz1.z), f2bf(bf2f(c.w) * rz1.w));
}

// ---------------- Kernel C: out^T = V'^T @ E^T (k-split-4, atomics) -------
// Block = (batch, 128-q block, k-quarter). Wave = 32q x 256d. 18 LDS reads
// feed 32 MFMAs per 32-key iter; E^T + V' double-buffered via gll (48KB).
__global__ __launch_bounds__(256, 2) void pv_gemm(
    const u16* __restrict__ Ef, const u16* __restrict__ Vf, float* __restrict__ out)
{
    __shared__ __align__(16) u16 Els[2][4096];    // 2 x 8KB  (8 E frags)
    __shared__ __align__(16) u16 Vls[2][8192];    // 2 x 16KB (16 V frags)
    const int tid = threadIdx.x, blk = blockIdx.x;
    const int xcd = blk & 7, idx = blk >> 3;
    const int b  = xcd >> 1;                       // batch on 2 XCDs
    const int ks = ((xcd & 1) << 1) | (idx & 1);   // key-quarter
    const int qb = idx >> 1;                       // q-block 0..31 (128 rows)
    const int w = tid >> 6, l = tid & 63, lr = l & 15, lg = l >> 4;
    const int qt0 = qb * 8;

    #define STAGE_KV(it_, nb_) do { \
        const int kc_ = ks * 32 + (it_); \
        gll16(Ef + e_base(b, kc_, qt0 + w * 2)     + l * 8, &Els[nb_][(w * 2) * 512]); \
        gll16(Ef + e_base(b, kc_, qt0 + w * 2 + 1) + l * 8, &Els[nb_][(w * 2 + 1) * 512]); \
        const size_t vb = (size_t)(b * 64 + (kc_ >> 1)) * 16384 + (kc_ & 1) * 512; \
        _Pragma("unroll") \
        for (int f_ = 0; f_ < 4; ++f_) \
            gll16(Vf + vb + (w * 4 + f_) * 1024 + l * 8, &Vls[nb_][(w * 4 + f_) * 512]); \
    } while (0)

    STAGE_KV(0, 0);
    __syncthreads();

    f32x4 acc[2][16] = {};

    for (int it = 0; it < 32; ++it) {
        const int cur = it & 1;
        if (it < 31) STAGE_KV(it + 1, cur ^ 1);

        bf16x8 ef0 = *reinterpret_cast<const bf16x8*>(&Els[cur][(w * 2) * 512 + l * 8]);
        bf16x8 ef1 = *reinterpret_cast<const bf16x8*>(&Els[cur][(w * 2 + 1) * 512 + l * 8]);
        #pragma unroll
        for (int dt = 0; dt < 16; ++dt) {
            bf16x8 vfr = *reinterpret_cast<const bf16x8*>(&Vls[cur][dt * 512 + l * 8]);
            acc[0][dt] = __builtin_amdgcn_mfma_f32_16x16x32_bf16(vfr, ef0, acc[0][dt], 0, 0, 0);
            acc[1][dt] = __builtin_amdgcn_mfma_f32_16x16x32_bf16(vfr, ef1, acc[1][dt], 0, 0, 0);
        }
        __syncthreads();
    }

    // epilogue: C rows = d (lg*4+r), cols = q (lr); 4 contributions per elem
    #pragma unroll
    for (int qt = 0; qt < 2; ++qt) {
        const int q = qb * 128 + w * 32 + qt * 16 + lr;
        float* orow = out + (size_t)(b * S_LEN + q) * D_DIM;
        #pragma unroll
        for (int dt = 0; dt < 16; ++dt) {
            #pragma unroll
            for (int r = 0; r < 4; ++r)
                unsafeAtomicAdd(&orow[dt * 16 + lg * 4 + r], acc[qt][dt][r]);
        }
    }
    #undef STAGE_KV
}

// ================= FALLBACK (round-5 fused path, ~25.6MB ws) ==============
__global__ __launch_bounds__(256) void col_denom_fb(
    const u16* __restrict__ Qf, const u16* __restrict__ Kf, float* __restrict__ LZ)
{
    __shared__ __align__(16) u16 Qls[2][16384];
    const int tid = threadIdx.x, blk = blockIdx.x;
    const int b = (blk >> 1) & 3;
    const int t = ((blk >> 3) << 1) | (blk & 1);
    const int w = tid >> 6, l = tid & 63, lr = l & 15, lg = l >> 4;
    const int k0 = t * 64;
    const int base_tq = b * 256;

    const int tkw = base_tq + (k0 >> 4) + w;
    bf16x8 kreg[8];
    #pragma unroll
    for (int kk = 0; kk < 8; ++kk)
        kreg[kk] = *reinterpret_cast<const bf16x8*>(Kf + fr_qk(tkw, kk) + l * 8);

    #define STAGE_Q(qt_, nb_) do { \
        const u16* g_ = Qf + ((size_t)(base_tq + (qt_) * 4)) * 4096 + (w * 8) * 512 + l * 8; \
        u16* d_ = &Qls[nb_][(w * 8) * 512]; \
        _Pragma("unroll") \
        for (int f_ = 0; f_ < 8; ++f_) gll16(g_ + f_ * 512, d_ + f_ * 512); \
    } while (0)

    STAGE_Q(0, 0);
    __syncthreads();

    float Z[4] = {};
    const float SC = 0.0625f;

    for (int qt = 0; qt < 64; ++qt) {
        const int cur = qt & 1;
        if (qt < 63) STAGE_Q(qt + 1, cur ^ 1);
        f32x4 acc[4] = {};
        #pragma unroll
        for (int kk = 0; kk < 8; ++kk) {
            #pragma unroll
            for (int cf = 0; cf < 4; ++cf) {
                bf16x8 qfr = *reinterpret_cast<const bf16x8*>(
                    &Qls[cur][(cf * 8 + kk) * 512 + l * 8]);
                acc[cf] = __builtin_amdgcn_mfma_f32_16x16x32_bf16(kreg[kk], qfr, acc[cf], 0, 0, 0);
            }
        }
        #pragma unroll
        for (int cf = 0; cf < 4; ++cf)
            #pragma unroll
            for (int r = 0; r < 4; ++r)
                Z[r] += __expf(acc[cf][r] * SC);
        __syncthreads();
    }
    #pragma unroll
    for (int r = 0; r < 4; ++r) {
        float z = Z[r];
        z += __shfl_xor(z, 1);
        z += __shfl_xor(z, 2);
        z += __shfl_xor(z, 4);
        z += __shfl_xor(z, 8);
        if (lr == 0) LZ[b * S_LEN + k0 + w * 16 + lg * 4 + r] = logf(z);
    }
    #undef STAGE_Q
}

__global__ __launch_bounds__(256) void attn_out_fb(
    const u16* __restrict__ Qf, const u16* __restrict__ Kf, const u16* __restrict__ Vf,
    const float* __restrict__ LZ, float* __restrict__ out)
{
    __shared__ __align__(16) u16 Kls[2][16384];
    __shared__ __align__(16) u16 Vls[2][16384];
    __shared__ __align__(16) u16 ps[4][1152];

    const int tid = threadIdx.x, blk = blockIdx.x;
    const int b = (blk >> 1) & 3;
    const int t = ((blk >> 3) << 1) | (blk & 1);
    const int w = tid >> 6, l = tid & 63, lr = l & 15, lg = l >> 4;
    const int q0 = t * 64 + w * 16;
    const int base_tk = b * 256;

    const int tq = base_tk + (q0 >> 4);
    bf16x8 qreg[8];
    #pragma unroll
    for (int kk = 0; kk < 8; ++kk)
        qreg[kk] = *reinterpret_cast<const bf16x8*>(Qf + fr_qk(tq, kk) + l * 8);

    #define STAGE_KV(kt_, nb_) do { \
        if (w < 2) { \
            const u16* g_ = Kf + ((size_t)(base_tk + (kt_) * 4)) * 4096 + (w * 16) * 512 + l * 8; \
            u16* d_ = &Kls[nb_][(w * 16) * 512]; \
            _Pragma("unroll") \
            for (int f_ = 0; f_ < 16; ++f_) gll16(g_ + f_ * 512, d_ + f_ * 512); \
        } else { \
            const u16* g_ = Vf + ((size_t)(b * 64 + (kt_))) * 16384 + ((w - 2) * 16) * 512 + l * 8; \
            u16* d_ = &Vls[nb_][((w - 2) * 16) * 512]; \
            _Pragma("unroll") \
            for (int f_ = 0; f_ < 16; ++f_) gll16(g_ + f_ * 512, d_ + f_ * 512); \
        } \
    } while (0)

    STAGE_KV(0, 0);
    __syncthreads();

    f32x4 oacc[16] = {};
    const float SC = 0.0625f;

    for (int kt = 0; kt < 64; ++kt) {
        const int cur = kt & 1;
        if (kt < 63) STAGE_KV(kt + 1, cur ^ 1);
        float Lv[4];
        #pragma unroll
        for (int cf = 0; cf < 4; ++cf)
            Lv[cf] = LZ[b * S_LEN + kt * 64 + cf * 16 + lr];
        f32x4 sacc[4] = {};
        #pragma unroll
        for (int kk = 0; kk < 8; ++kk) {
            #pragma unroll
            for (int cf = 0; cf < 4; ++cf) {
                bf16x8 kfr = *reinterpret_cast<const bf16x8*>(
                    &Kls[cur][(cf * 8 + kk) * 512 + l * 8]);
                sacc[cf] = __builtin_amdgcn_mfma_f32_16x16x32_bf16(qreg[kk], kfr, sacc[cf], 0, 0, 0);
            }
        }
        #pragma unroll
        for (int cf = 0; cf < 4; ++cf) {
            #pragma unroll
            for (int r = 0; r < 4; ++r) {
                float p = __expf(fmaf(sacc[cf][r], SC, -Lv[cf]));
                ps[w][(lg * 4 + r) * 72 + cf * 16 + lr] = f2bf(p);
            }
        }
        #pragma unroll
        for (int kk2 = 0; kk2 < 2; ++kk2) {
            bf16x8 af = *reinterpret_cast<const bf16x8*>(&ps[w][lr * 72 + kk2 * 32 + lg * 8]);
            #pragma unroll
            for (int cf2 = 0; cf2 < 16; ++cf2) {
                bf16x8 vfr = *reinterpret_cast<const bf16x8*>(
                    &Vls[cur][(cf2 * 2 + kk2) * 512 + l * 8]);
                oacc[cf2] = __builtin_amdgcn_mfma_f32_16x16x32_bf16(af, vfr, oacc[cf2], 0, 0, 0);
            }
        }
        __syncthreads();
    }
    #pragma unroll
    for (int cf2 = 0; cf2 < 16; ++cf2) {
        #pragma unroll
        for (int r = 0; r < 4; ++r) {
            int row = q0 + lg * 4 + r;
            out[((size_t)(b * S_LEN + row)) * D_DIM + cf2 * 16 + lr] = oacc[cf2][r];
        }
    }
    #undef STAGE_KV
}

// ---------------- launcher ------------------------------------------------
extern "C" void kernel_launch(void* const* d_in, const int* in_sizes, int n_in,
                              void* d_out, int out_size, void* d_ws, size_t ws_size,
                              hipStream_t stream) {
    const float* x  = (const float*)d_in[0];
    const float* Wq = (const float*)d_in[1];
    const float* bq = (const float*)d_in[2];
    const float* Wk = (const float*)d_in[3];
    const float* bk = (const float*)d_in[4];
    const float* Wv = (const float*)d_in[5];
    const float* bv = (const float*)d_in[6];
    float* out = (float*)d_out;

    u16* Qf = (u16*)d_ws;                              // 8 MB
    u16* Kf = Qf + (size_t)NROW * D_DIM;               // 8 MB
    u16* Vf = Kf + (size_t)NROW * D_DIM;               // 8 MB
    u16* Wf = Vf + (size_t)NROW * D_DIM;               // 384 KB
    float* Zp = (float*)(Wf + 196608);                 // 256 KB (4 partials)
    float* rZ = Zp + 4 * NROW;                         // 64 KB
    u16* Ef = (u16*)(rZ + NROW);                       // 134.2 MB

    const size_t need = (size_t)((char*)Ef - (char*)d_ws) + (size_t)4 * 32768 * 512 * 2;

    if (ws_size >= need) {
        hipMemsetAsync(out, 0, (size_t)NROW * D_DIM * sizeof(float), stream);
        wconv<<<96, 256, 0, stream>>>(Wq, Wk, Wv, Wf);
        qkv_proj<<<NROW / 32, 256, 0, stream>>>(x, Wf, bq, bk, bv, Qf, Kf, Vf);
        score_exp<<<512, 256, 0, stream>>>(Qf, Kf, Ef, Zp);
        zrecip<<<NROW / 256, 256, 0, stream>>>(Zp, rZ);
        vscale<<<2048, 256, 0, stream>>>(Vf, rZ);
        pv_gemm<<<512, 256, 0, stream>>>(Ef, Vf, out);
    } else {
        float* LZ = Zp;
        wconv<<<96, 256, 0, stream>>>(Wq, Wk, Wv, Wf);
        qkv_proj<<<NROW / 32, 256, 0, stream>>>(x, Wf, bq, bk, bv, Qf, Kf, Vf);
        col_denom_fb<<<256, 256, 0, stream>>>(Qf, Kf, LZ);
        attn_out_fb<<<256, 256, 0, stream>>>(Qf, Kf, Vf, LZ, out);
    }
}

// Round 8
// 189.093 us; speedup vs baseline: 1.7388x; 1.7388x over previous
//
#include <hip/hip_runtime.h>

typedef short bf16x8 __attribute__((ext_vector_type(8)));
typedef float f32x4 __attribute__((ext_vector_type(4)));
typedef unsigned short u16;

#define S_LEN 4096
#define D_DIM 256
#define NROW  16384   // B*S

__device__ __forceinline__ u16 f2bf(float f) {
    union { float f; unsigned u; } v; v.f = f;
    unsigned r = v.u + 0x7FFFu + ((v.u >> 16) & 1u);
    return (u16)(r >> 16);
}

// Fragment-linear layouts (bf16):
//  Q/K/W: row-tile t (16 rows), kk (32-depth chunk): frag = t*4096 + kk*512,
//         elem(row_local, col) at ((col>>3)&3)*128 + row_local*8 + (col&7).
//         Lane l reads frag + l*8 -> row=l&15, k=(l>>4)*8+e. 1KB coalesced.
//  V^T:   panel p = b*64+kt64 (64 keys x 256 d): frag(dt,kk2) = p*16384+(dt*2+kk2)*512.
__device__ __forceinline__ size_t fr_qk(int t, int kk) {
    return (size_t)t * 4096 + kk * 512;
}
__device__ __forceinline__ size_t fr_v(int p, int dt, int kk2) {
    return (size_t)p * 16384 + (dt * 2 + kk2) * 512;
}

// async global->LDS, 16B/lane: lane l's 16B from g+l*8(u16) lands at lds+l*16.
__device__ __forceinline__ void gll16(const u16* g, u16* l) {
    __builtin_amdgcn_global_load_lds(
        (const __attribute__((address_space(1))) unsigned int*)g,
        (__attribute__((address_space(3))) unsigned int*)l, 16, 0, 0);
}

// ---------------- Kernel W: W f32 -> bf16 fragments -----------------------
__global__ __launch_bounds__(256) void wconv(
    const float* __restrict__ Wq, const float* __restrict__ Wk,
    const float* __restrict__ Wv, u16* __restrict__ Wf)
{
    int i = blockIdx.x * 256 + threadIdx.x;
    int m = i >> 13;
    int idx = i & 8191;
    int ocol = idx >> 5;
    int d0 = (idx & 31) * 8;
    const float* s = (m == 0 ? Wq : (m == 1 ? Wk : Wv)) + ocol * 256 + d0;
    float4 v0 = *reinterpret_cast<const float4*>(s);
    float4 v1 = *reinterpret_cast<const float4*>(s + 4);
    union { ushort4 h[2]; int4 q; } t;
    t.h[0] = make_ushort4(f2bf(v0.x), f2bf(v0.y), f2bf(v0.z), f2bf(v0.w));
    t.h[1] = make_ushort4(f2bf(v1.x), f2bf(v1.y), f2bf(v1.z), f2bf(v1.w));
    size_t off = (size_t)m * 65536 + fr_qk(ocol >> 4, d0 >> 5)
               + ((d0 >> 3) & 3) * 128 + (ocol & 15) * 8;
    *reinterpret_cast<int4*>(Wf + off) = t.q;
}

// ---------------- Kernel A: QKV projection (32 rows/block) ----------------
__global__ __launch_bounds__(256) void qkv_proj(
    const float* __restrict__ x, const u16* __restrict__ Wf,
    const float* __restrict__ bq, const float* __restrict__ bk,
    const float* __restrict__ bv,
    u16* __restrict__ Qf, u16* __restrict__ Kf, u16* __restrict__ Vf)
{
    __shared__ u16 xs[32][264];
    const int tid = threadIdx.x;
    const int r0 = blockIdx.x * 32;

    #pragma unroll
    for (int i = 0; i < 8; ++i) {
        int c = i * 256 + tid;
        int row = c >> 6, c4 = c & 63;
        float4 v = reinterpret_cast<const float4*>(x + (size_t)(r0 + row) * D_DIM)[c4];
        *reinterpret_cast<ushort4*>(&xs[row][c4 * 4]) =
            make_ushort4(f2bf(v.x), f2bf(v.y), f2bf(v.z), f2bf(v.w));
    }
    __syncthreads();

    const int w = tid >> 6, l = tid & 63, lr = l & 15, lg = l >> 4;
    const int c0 = w * 64;

    bf16x8 a[2][8];
    #pragma unroll
    for (int qs = 0; qs < 2; ++qs)
        #pragma unroll
        for (int kk = 0; kk < 8; ++kk)
            a[qs][kk] = *reinterpret_cast<const bf16x8*>(&xs[qs * 16 + lr][kk * 32 + lg * 8]);

    const float* Bs[3] = {bq, bk, bv};

    #pragma unroll
    for (int m = 0; m < 3; ++m) {
        const u16* Wm = Wf + (size_t)m * 65536;
        f32x4 acc[2][4] = {};
        #pragma unroll
        for (int kk = 0; kk < 8; ++kk) {
            #pragma unroll
            for (int cf = 0; cf < 4; ++cf) {
                bf16x8 wfr = *reinterpret_cast<const bf16x8*>(
                    Wm + fr_qk(w * 4 + cf, kk) + l * 8);
                acc[0][cf] = __builtin_amdgcn_mfma_f32_16x16x32_bf16(a[0][kk], wfr, acc[0][cf], 0, 0, 0);
                acc[1][cf] = __builtin_amdgcn_mfma_f32_16x16x32_bf16(a[1][kk], wfr, acc[1][cf], 0, 0, 0);
            }
        }
        if (m < 2) {
            u16* outp = (m == 0) ? Qf : Kf;
            int t = r0 >> 4;
            #pragma unroll
            for (int qs = 0; qs < 2; ++qs) {
                #pragma unroll
                for (int cf = 0; cf < 4; ++cf) {
                    int col = c0 + cf * 16 + lr;
                    float bias = Bs[m][col];
                    size_t base = fr_qk(t + qs, col >> 5) + ((col >> 3) & 3) * 128 + (col & 7);
                    #pragma unroll
                    for (int r = 0; r < 4; ++r)
                        outp[base + (lg * 4 + r) * 8] = f2bf(acc[qs][cf][r] + bias);
                }
            }
        } else {
            int p  = (r0 >> 12) * 64 + ((r0 & 4095) >> 6);
            int kb = r0 & 63;
            #pragma unroll
            for (int qs = 0; qs < 2; ++qs) {
                #pragma unroll
                for (int cf = 0; cf < 4; ++cf) {
                    int d = c0 + cf * 16 + lr;
                    float bias = bv[d];
                    #pragma unroll
                    for (int r = 0; r < 4; ++r) {
                        int key = kb + qs * 16 + lg * 4 + r;
                        size_t off = fr_v(p, d >> 4, key >> 5)
                                   + ((key >> 3) & 3) * 128 + (d & 15) * 8 + (key & 7);
                        Vf[off] = f2bf(acc[qs][cf][r] + bias);
                    }
                }
            }
        }
    }
}

// ---------------- Kernel B: partial column sums (q-half split) ------------
// Zp[qhalf][b,k] = sum over 2048 queries of exp(s/16). Block = 64 keys
// (wave w holds 16 in regs) x one q-half; 64 iters of 32-q panels.
__global__ __launch_bounds__(256, 4) void col_denom(
    const u16* __restrict__ Qf, const u16* __restrict__ Kf, float* __restrict__ Zp)
{
    __shared__ __align__(16) u16 Qls[2][8192];    // 2 x 16KB (32-q panels)
    const int tid = threadIdx.x, blk = blockIdx.x;
    const int xcd = blk & 7;
    const int b = xcd >> 1, qhalf = xcd & 1;      // XCD-clustered
    const int idx = blk >> 3;                     // key-tile 0..63
    const int w = tid >> 6, l = tid & 63, lr = l & 15, lg = l >> 4;
    const int k0 = idx * 64;

    const int tkw = b * 256 + idx * 4 + w;
    bf16x8 kreg[8];
    #pragma unroll
    for (int kk = 0; kk < 8; ++kk)
        kreg[kk] = *reinterpret_cast<const bf16x8*>(Kf + fr_qk(tkw, kk) + l * 8);

    // stage one 32-q panel (16 frags, contiguous 16KB): wave w frags w*4..+3
    #define STAGE_Q(qt_, nb_) do { \
        const u16* g_ = Qf + ((size_t)(b * 256 + (qt_) * 2)) * 4096 + (w * 4) * 512 + l * 8; \
        u16* d_ = &Qls[nb_][(w * 4) * 512]; \
        _Pragma("unroll") \
        for (int f_ = 0; f_ < 4; ++f_) gll16(g_ + f_ * 512, d_ + f_ * 512); \
    } while (0)

    const int qt0 = qhalf * 64;
    STAGE_Q(qt0, 0);
    __syncthreads();

    float Z[4] = {};
    const float SC = 0.0625f;

    for (int it = 0; it < 64; ++it) {
        const int cur = it & 1;
        if (it < 63) STAGE_Q(qt0 + it + 1, cur ^ 1);

        f32x4 acc[2] = {};
        #pragma unroll
        for (int kk = 0; kk < 8; ++kk) {
            #pragma unroll
            for (int qf = 0; qf < 2; ++qf) {
                bf16x8 qfr = *reinterpret_cast<const bf16x8*>(
                    &Qls[cur][(qf * 8 + kk) * 512 + l * 8]);
                acc[qf] = __builtin_amdgcn_mfma_f32_16x16x32_bf16(kreg[kk], qfr, acc[qf], 0, 0, 0);
            }
        }
        #pragma unroll
        for (int qf = 0; qf < 2; ++qf)
            #pragma unroll
            for (int r = 0; r < 4; ++r)
                Z[r] += __expf(acc[qf][r] * SC);
        __syncthreads();
    }

    #pragma unroll
    for (int r = 0; r < 4; ++r) {
        float z = Z[r];
        z += __shfl_xor(z, 1);
        z += __shfl_xor(z, 2);
        z += __shfl_xor(z, 4);
        z += __shfl_xor(z, 8);
        if (lr == 0)
            Zp[qhalf * NROW + b * S_LEN + k0 + w * 16 + lg * 4 + r] = z;
    }
    #undef STAGE_Q
}

// ---------------- Kernel Z: LZ = log(Zp0 + Zp1) ---------------------------
__global__ __launch_bounds__(256) void zlog(
    const float* __restrict__ Zp, float* __restrict__ LZ)
{
    int i = blockIdx.x * 256 + threadIdx.x;
    LZ[i] = logf(Zp[i] + Zp[NROW + i]);
}

// ---------------- Kernel C: out += (exp(S)/Z) @ V (key-half split) --------
// Block = 64 q rows (wave w owns 16) x one key-half (64 panels of 32 keys).
// K+V double-buffered in 70KB LDS -> 2 blocks/CU (2 waves/SIMD). Epilogue:
// 2 commutative atomic contributions per element (bit-deterministic).
__global__ __launch_bounds__(256, 2) void attn_out(
    const u16* __restrict__ Qf, const u16* __restrict__ Kf, const u16* __restrict__ Vf,
    const float* __restrict__ LZ, float* __restrict__ out)
{
    __shared__ __align__(16) u16 Kls[2][8192];    // 2 x 16KB K panels (32 keys)
    __shared__ __align__(16) u16 Vls[2][8192];    // 2 x 16KB V^T panels
    __shared__ __align__(16) u16 ps[4][640];      // per-wave P tile [16][40]

    const int tid = threadIdx.x, blk = blockIdx.x;
    const int xcd = blk & 7;
    const int b = xcd >> 1, khalf = xcd & 1;      // XCD-clustered (b,khalf)
    const int idx = blk >> 3;                     // q-tile 0..63
    const int w = tid >> 6, l = tid & 63, lr = l & 15, lg = l >> 4;
    const int q0 = idx * 64 + w * 16;
    const int base_tk = b * 256;                  // (b*S_LEN)/16

    const int tq = base_tk + (q0 >> 4);
    bf16x8 qreg[8];
    #pragma unroll
    for (int kk = 0; kk < 8; ++kk)
        qreg[kk] = *reinterpret_cast<const bf16x8*>(Qf + fr_qk(tq, kk) + l * 8);

    // stage one 32-key K panel (16 frags contiguous) + 16 V frags.
    // waves 0,1: K (8 frags each); waves 2,3: V (8 frags each).
    #define STAGE_KV(kt_, nb_) do { \
        if (w < 2) { \
            const u16* g_ = Kf + ((size_t)(base_tk + (kt_) * 2)) * 4096 + (w * 8) * 512 + l * 8; \
            u16* d_ = &Kls[nb_][(w * 8) * 512]; \
            _Pragma("unroll") \
            for (int f_ = 0; f_ < 8; ++f_) gll16(g_ + f_ * 512, d_ + f_ * 512); \
        } else { \
            const size_t vb_ = ((size_t)(b * 64 + ((kt_) >> 1))) * 16384 + ((kt_) & 1) * 512; \
            const int dt0_ = (w - 2) * 8; \
            _Pragma("unroll") \
            for (int f_ = 0; f_ < 8; ++f_) \
                gll16(Vf + vb_ + (size_t)(dt0_ + f_) * 1024 + l * 8, &Vls[nb_][(dt0_ + f_) * 512]); \
        } \
    } while (0)

    const int kt0 = khalf * 64;
    STAGE_KV(kt0, 0);
    __syncthreads();

    f32x4 oacc[16] = {};
    const float SC = 0.0625f;

    for (int it = 0; it < 64; ++it) {
        const int kt = kt0 + it;
        const int cur = it & 1;
        if (it < 63) STAGE_KV(kt + 1, cur ^ 1);

        float Lv0 = LZ[b * S_LEN + kt * 32 + lr];
        float Lv1 = LZ[b * S_LEN + kt * 32 + 16 + lr];

        // QK^T from staged K: 16 frag reads -> 16 MFMAs
        f32x4 sacc[2] = {};
        #pragma unroll
        for (int kk = 0; kk < 8; ++kk) {
            #pragma unroll
            for (int cf = 0; cf < 2; ++cf) {
                bf16x8 kfr = *reinterpret_cast<const bf16x8*>(
                    &Kls[cur][(cf * 8 + kk) * 512 + l * 8]);
                sacc[cf] = __builtin_amdgcn_mfma_f32_16x16x32_bf16(qreg[kk], kfr, sacc[cf], 0, 0, 0);
            }
        }
        // P = exp(s/16 - LZ) -> per-wave LDS (A-operand layout, 16q x 32k)
        #pragma unroll
        for (int cf = 0; cf < 2; ++cf) {
            float Lv = cf ? Lv1 : Lv0;
            #pragma unroll
            for (int r = 0; r < 4; ++r) {
                float p = __expf(fmaf(sacc[cf][r], SC, -Lv));
                ps[w][(lg * 4 + r) * 40 + cf * 16 + lr] = f2bf(p);
            }
        }
        // PV from staged V^T: 1 P read + 16 V reads -> 16 MFMAs
        bf16x8 af = *reinterpret_cast<const bf16x8*>(&ps[w][lr * 40 + lg * 8]);
        #pragma unroll
        for (int dt = 0; dt < 16; ++dt) {
            bf16x8 vfr = *reinterpret_cast<const bf16x8*>(&Vls[cur][dt * 512 + l * 8]);
            oacc[dt] = __builtin_amdgcn_mfma_f32_16x16x32_bf16(af, vfr, oacc[dt], 0, 0, 0);
        }
        __syncthreads();
    }

    // epilogue: 2 commutative atomic contributions per element
    #pragma unroll
    for (int dt = 0; dt < 16; ++dt) {
        #pragma unroll
        for (int r = 0; r < 4; ++r) {
            int row = q0 + lg * 4 + r;
            unsafeAtomicAdd(&out[((size_t)(b * S_LEN + row)) * D_DIM + dt * 16 + lr],
                            oacc[dt][r]);
        }
    }
    #undef STAGE_KV
}

// ---------------- launcher ------------------------------------------------
extern "C" void kernel_launch(void* const* d_in, const int* in_sizes, int n_in,
                              void* d_out, int out_size, void* d_ws, size_t ws_size,
                              hipStream_t stream) {
    const float* x  = (const float*)d_in[0];
    const float* Wq = (const float*)d_in[1];
    const float* bq = (const float*)d_in[2];
    const float* Wk = (const float*)d_in[3];
    const float* bk = (const float*)d_in[4];
    const float* Wv = (const float*)d_in[5];
    const float* bv = (const float*)d_in[6];
    float* out = (float*)d_out;

    u16* Qf = (u16*)d_ws;                              // 8 MB (fragment layout)
    u16* Kf = Qf + (size_t)NROW * D_DIM;               // 8 MB
    u16* Vf = Kf + (size_t)NROW * D_DIM;               // 8 MB
    u16* Wf = Vf + (size_t)NROW * D_DIM;               // 384 KB
    float* Zp = (float*)(Wf + 196608);                 // 128 KB (2 q-half partials)
    float* LZ = Zp + 2 * NROW;                         // 64 KB

    hipMemsetAsync(out, 0, (size_t)NROW * D_DIM * sizeof(float), stream);

    wconv<<<96, 256, 0, stream>>>(Wq, Wk, Wv, Wf);
    qkv_proj<<<NROW / 32, 256, 0, stream>>>(x, Wf, bq, bk, bv, Qf, Kf, Vf);
    col_denom<<<512, 256, 0, stream>>>(Qf, Kf, Zp);
    zlog<<<NROW / 256, 256, 0, stream>>>(Zp, LZ);
    attn_out<<<512, 256, 0, stream>>>(Qf, Kf, Vf, LZ, out);
}

// Round 9
// 185.998 us; speedup vs baseline: 1.7678x; 1.0166x over previous
//
#include <hip/hip_runtime.h>

typedef short bf16x8 __attribute__((ext_vector_type(8)));
typedef float f32x4 __attribute__((ext_vector_type(4)));
typedef unsigned short u16;

#define S_LEN 4096
#define D_DIM 256
#define NROW  16384   // B*S

__device__ __forceinline__ u16 f2bf(float f) {
    union { float f; unsigned u; } v; v.f = f;
    unsigned r = v.u + 0x7FFFu + ((v.u >> 16) & 1u);
    return (u16)(r >> 16);
}

// Fragment-linear layouts (bf16):
//  Q/K/W: row-tile t (16 rows), kk (32-depth chunk): frag = t*4096 + kk*512,
//         elem(row_local, col) at ((col>>3)&3)*128 + row_local*8 + (col&7).
//         Lane l reads frag + l*8 -> row=l&15, depth=(l>>4)*8+e. 1KB coalesced.
//  V^T:   panel p = b*64+kt64 (64 keys x 256 d): frag(dt,kk2) = p*16384+(dt*2+kk2)*512.
__device__ __forceinline__ size_t fr_qk(int t, int kk) {
    return (size_t)t * 4096 + kk * 512;
}
__device__ __forceinline__ size_t fr_v(int p, int dt, int kk2) {
    return (size_t)p * 16384 + (dt * 2 + kk2) * 512;
}

// async global->LDS, 16B/lane: lane l's 16B from g+l*8(u16) lands at lds+l*16.
__device__ __forceinline__ void gll16(const u16* g, u16* l) {
    __builtin_amdgcn_global_load_lds(
        (const __attribute__((address_space(1))) unsigned int*)g,
        (__attribute__((address_space(3))) unsigned int*)l, 16, 0, 0);
}

// ---------------- Kernel W: W f32 -> bf16 fragments -----------------------
__global__ __launch_bounds__(256) void wconv(
    const float* __restrict__ Wq, const float* __restrict__ Wk,
    const float* __restrict__ Wv, u16* __restrict__ Wf)
{
    int i = blockIdx.x * 256 + threadIdx.x;
    int m = i >> 13;
    int idx = i & 8191;
    int ocol = idx >> 5;
    int d0 = (idx & 31) * 8;
    const float* s = (m == 0 ? Wq : (m == 1 ? Wk : Wv)) + ocol * 256 + d0;
    float4 v0 = *reinterpret_cast<const float4*>(s);
    float4 v1 = *reinterpret_cast<const float4*>(s + 4);
    union { ushort4 h[2]; int4 q; } t;
    t.h[0] = make_ushort4(f2bf(v0.x), f2bf(v0.y), f2bf(v0.z), f2bf(v0.w));
    t.h[1] = make_ushort4(f2bf(v1.x), f2bf(v1.y), f2bf(v1.z), f2bf(v1.w));
    size_t off = (size_t)m * 65536 + fr_qk(ocol >> 4, d0 >> 5)
               + ((d0 >> 3) & 3) * 128 + (ocol & 15) * 8;
    *reinterpret_cast<int4*>(Wf + off) = t.q;
}

// ---------------- Kernel A: QKV projection (32 rows/block) ----------------
__global__ __launch_bounds__(256) void qkv_proj(
    const float* __restrict__ x, const u16* __restrict__ Wf,
    const float* __restrict__ bq, const float* __restrict__ bk,
    const float* __restrict__ bv,
    u16* __restrict__ Qf, u16* __restrict__ Kf, u16* __restrict__ Vf)
{
    __shared__ u16 xs[32][264];
    const int tid = threadIdx.x;
    const int r0 = blockIdx.x * 32;

    #pragma unroll
    for (int i = 0; i < 8; ++i) {
        int c = i * 256 + tid;
        int row = c >> 6, c4 = c & 63;
        float4 v = reinterpret_cast<const float4*>(x + (size_t)(r0 + row) * D_DIM)[c4];
        *reinterpret_cast<ushort4*>(&xs[row][c4 * 4]) =
            make_ushort4(f2bf(v.x), f2bf(v.y), f2bf(v.z), f2bf(v.w));
    }
    __syncthreads();

    const int w = tid >> 6, l = tid & 63, lr = l & 15, lg = l >> 4;
    const int c0 = w * 64;

    bf16x8 a[2][8];
    #pragma unroll
    for (int qs = 0; qs < 2; ++qs)
        #pragma unroll
        for (int kk = 0; kk < 8; ++kk)
            a[qs][kk] = *reinterpret_cast<const bf16x8*>(&xs[qs * 16 + lr][kk * 32 + lg * 8]);

    const float* Bs[3] = {bq, bk, bv};

    #pragma unroll
    for (int m = 0; m < 3; ++m) {
        const u16* Wm = Wf + (size_t)m * 65536;
        f32x4 acc[2][4] = {};
        #pragma unroll
        for (int kk = 0; kk < 8; ++kk) {
            #pragma unroll
            for (int cf = 0; cf < 4; ++cf) {
                bf16x8 wfr = *reinterpret_cast<const bf16x8*>(
                    Wm + fr_qk(w * 4 + cf, kk) + l * 8);
                acc[0][cf] = __builtin_amdgcn_mfma_f32_16x16x32_bf16(a[0][kk], wfr, acc[0][cf], 0, 0, 0);
                acc[1][cf] = __builtin_amdgcn_mfma_f32_16x16x32_bf16(a[1][kk], wfr, acc[1][cf], 0, 0, 0);
            }
        }
        if (m < 2) {
            u16* outp = (m == 0) ? Qf : Kf;
            int t = r0 >> 4;
            #pragma unroll
            for (int qs = 0; qs < 2; ++qs) {
                #pragma unroll
                for (int cf = 0; cf < 4; ++cf) {
                    int col = c0 + cf * 16 + lr;
                    float bias = Bs[m][col];
                    size_t base = fr_qk(t + qs, col >> 5) + ((col >> 3) & 3) * 128 + (col & 7);
                    #pragma unroll
                    for (int r = 0; r < 4; ++r)
                        outp[base + (lg * 4 + r) * 8] = f2bf(acc[qs][cf][r] + bias);
                }
            }
        } else {
            int p  = (r0 >> 12) * 64 + ((r0 & 4095) >> 6);
            int kb = r0 & 63;
            #pragma unroll
            for (int qs = 0; qs < 2; ++qs) {
                #pragma unroll
                for (int cf = 0; cf < 4; ++cf) {
                    int d = c0 + cf * 16 + lr;
                    float bias = bv[d];
                    #pragma unroll
                    for (int r = 0; r < 4; ++r) {
                        int key = kb + qs * 16 + lg * 4 + r;
                        size_t off = fr_v(p, d >> 4, key >> 5)
                                   + ((key >> 3) & 3) * 128 + (d & 15) * 8 + (key & 7);
                        Vf[off] = f2bf(acc[qs][cf][r] + bias);
                    }
                }
            }
        }
    }
}

// ---------------- Kernel B: partial column sums (q-quarter split) ---------
// Zp[qq][b,k] = sum over 1024 queries of exp(s/16). Block = 128 keys
// (wave w holds 32 in regs -> each Q frag feeds 2 MFMAs) x one q-quarter.
__global__ __launch_bounds__(256, 2) void col_denom(
    const u16* __restrict__ Qf, const u16* __restrict__ Kf, float* __restrict__ Zp)
{
    __shared__ __align__(16) u16 Qls[2][8192];    // 2 x 16KB (32-q panels)
    const int tid = threadIdx.x, blk = blockIdx.x;
    const int xcd = blk & 7, sub = blk >> 3;      // sub 0..63
    const int b  = xcd >> 1;
    const int qq = ((xcd & 1) << 1) | (sub & 1);  // q-quarter 0..3
    const int ktile = sub >> 1;                   // 0..31 (128 keys)
    const int w = tid >> 6, l = tid & 63, lr = l & 15, lg = l >> 4;
    const int k0 = ktile * 128;

    bf16x8 kreg[2][8];
    #pragma unroll
    for (int ks = 0; ks < 2; ++ks) {
        const int tk = b * 256 + (k0 >> 4) + w * 2 + ks;
        #pragma unroll
        for (int kk = 0; kk < 8; ++kk)
            kreg[ks][kk] = *reinterpret_cast<const bf16x8*>(Kf + fr_qk(tk, kk) + l * 8);
    }

    // stage one 32-q panel (16 frags, 16KB): wave w stages frags w*4..w*4+3
    #define STAGE_Q(qt_, nb_) do { \
        const u16* g_ = Qf + ((size_t)(b * 256 + (qt_) * 2)) * 4096 + (w * 4) * 512 + l * 8; \
        u16* d_ = &Qls[nb_][(w * 4) * 512]; \
        _Pragma("unroll") \
        for (int f_ = 0; f_ < 4; ++f_) gll16(g_ + f_ * 512, d_ + f_ * 512); \
    } while (0)

    const int qt0 = qq * 32;                      // 32 panels of 32 q
    STAGE_Q(qt0, 0);
    __syncthreads();

    float Z[2][4] = {};
    const float SC = 0.0625f;

    for (int it = 0; it < 32; ++it) {
        const int cur = it & 1;
        if (it < 31) STAGE_Q(qt0 + it + 1, cur ^ 1);

        f32x4 acc[2][2] = {};
        #pragma unroll
        for (int kk = 0; kk < 8; ++kk) {
            #pragma unroll
            for (int qf = 0; qf < 2; ++qf) {
                bf16x8 qfr = *reinterpret_cast<const bf16x8*>(
                    &Qls[cur][(qf * 8 + kk) * 512 + l * 8]);
                acc[0][qf] = __builtin_amdgcn_mfma_f32_16x16x32_bf16(kreg[0][kk], qfr, acc[0][qf], 0, 0, 0);
                acc[1][qf] = __builtin_amdgcn_mfma_f32_16x16x32_bf16(kreg[1][kk], qfr, acc[1][qf], 0, 0, 0);
            }
        }
        #pragma unroll
        for (int ks = 0; ks < 2; ++ks)
            #pragma unroll
            for (int qf = 0; qf < 2; ++qf)
                #pragma unroll
                for (int r = 0; r < 4; ++r)
                    Z[ks][r] += __expf(acc[ks][qf][r] * SC);
        __syncthreads();
    }

    #pragma unroll
    for (int ks = 0; ks < 2; ++ks) {
        #pragma unroll
        for (int r = 0; r < 4; ++r) {
            float z = Z[ks][r];
            z += __shfl_xor(z, 1);
            z += __shfl_xor(z, 2);
            z += __shfl_xor(z, 4);
            z += __shfl_xor(z, 8);
            if (lr == 0)
                Zp[qq * NROW + b * S_LEN + k0 + w * 32 + ks * 16 + lg * 4 + r] = z;
        }
    }
    #undef STAGE_Q
}

// ---------------- Kernel Z: LZ = log(sum of 4 partials) -------------------
__global__ __launch_bounds__(256) void zlog(
    const float* __restrict__ Zp, float* __restrict__ LZ)
{
    int i = blockIdx.x * 256 + threadIdx.x;
    LZ[i] = logf(((Zp[i] + Zp[NROW + i]) + Zp[2 * NROW + i]) + Zp[3 * NROW + i]);
}

// ---------------- Kernel C: out += (exp(S)/Z) @ V (key-quarter split) -----
// Block = 128 q rows (wave w owns 32 = 2 q-tiles) x one key-quarter (32
// panels of 32 keys). Every K/V fragment read feeds 2 MFMAs. Epilogue:
// 4 commutative atomic contributions per element.
__global__ __launch_bounds__(256, 2) void attn_out(
    const u16* __restrict__ Qf, const u16* __restrict__ Kf, const u16* __restrict__ Vf,
    const float* __restrict__ LZ, float* __restrict__ out)
{
    __shared__ __align__(16) u16 Kls[2][8192];    // 2 x 16KB K panels (32 keys)
    __shared__ __align__(16) u16 Vls[2][8192];    // 2 x 16KB V^T panels
    __shared__ __align__(16) u16 ps[4][1280];     // per-wave P tile [32][40]

    const int tid = threadIdx.x, blk = blockIdx.x;
    const int xcd = blk & 7, sub = blk >> 3;      // sub 0..63
    const int b  = xcd >> 1;
    const int kq = ((xcd & 1) << 1) | (sub & 1);  // key-quarter 0..3
    const int qtile = sub >> 1;                   // 0..31 (128 q rows)
    const int w = tid >> 6, l = tid & 63, lr = l & 15, lg = l >> 4;
    const int q0 = qtile * 128 + w * 32;
    const int base_tk = b * 256;                  // (b*S_LEN)/16

    bf16x8 qreg[2][8];
    #pragma unroll
    for (int qs = 0; qs < 2; ++qs) {
        const int tq = base_tk + ((q0 + qs * 16) >> 4);
        #pragma unroll
        for (int kk = 0; kk < 8; ++kk)
            qreg[qs][kk] = *reinterpret_cast<const bf16x8*>(Qf + fr_qk(tq, kk) + l * 8);
    }

    // stage one 32-key K panel (16 frags) + 16 V frags.
    // waves 0,1: K (8 frags each); waves 2,3: V (8 frags each).
    #define STAGE_KV(kt_, nb_) do { \
        if (w < 2) { \
            const u16* g_ = Kf + ((size_t)(base_tk + (kt_) * 2)) * 4096 + (w * 8) * 512 + l * 8; \
            u16* d_ = &Kls[nb_][(w * 8) * 512]; \
            _Pragma("unroll") \
            for (int f_ = 0; f_ < 8; ++f_) gll16(g_ + f_ * 512, d_ + f_ * 512); \
        } else { \
            const size_t vb_ = ((size_t)(b * 64 + ((kt_) >> 1))) * 16384 + ((kt_) & 1) * 512; \
            const int dt0_ = (w - 2) * 8; \
            _Pragma("unroll") \
            for (int f_ = 0; f_ < 8; ++f_) \
                gll16(Vf + vb_ + (size_t)(dt0_ + f_) * 1024 + l * 8, &Vls[nb_][(dt0_ + f_) * 512]); \
        } \
    } while (0)

    const int kt0 = kq * 32;
    STAGE_KV(kt0, 0);
    __syncthreads();

    f32x4 oacc[2][16] = {};
    const float SC = 0.0625f;

    for (int it = 0; it < 32; ++it) {
        const int kt = kt0 + it;
        const int cur = it & 1;
        if (it < 31) STAGE_KV(kt + 1, cur ^ 1);

        // QK^T from staged K, per 16-key column tile (keeps sacc small)
        #pragma unroll
        for (int cf = 0; cf < 2; ++cf) {
            float Lv = LZ[b * S_LEN + kt * 32 + cf * 16 + lr];
            f32x4 sacc[2] = {};
            #pragma unroll
            for (int kk = 0; kk < 8; ++kk) {
                bf16x8 kfr = *reinterpret_cast<const bf16x8*>(
                    &Kls[cur][(cf * 8 + kk) * 512 + l * 8]);
                sacc[0] = __builtin_amdgcn_mfma_f32_16x16x32_bf16(qreg[0][kk], kfr, sacc[0], 0, 0, 0);
                sacc[1] = __builtin_amdgcn_mfma_f32_16x16x32_bf16(qreg[1][kk], kfr, sacc[1], 0, 0, 0);
            }
            #pragma unroll
            for (int qs = 0; qs < 2; ++qs) {
                #pragma unroll
                for (int r = 0; r < 4; ++r) {
                    float p = __expf(fmaf(sacc[qs][r], SC, -Lv));
                    ps[w][(qs * 16 + lg * 4 + r) * 40 + cf * 16 + lr] = f2bf(p);
                }
            }
        }
        // PV from staged V^T: each V frag feeds both q-tiles
        bf16x8 af0 = *reinterpret_cast<const bf16x8*>(&ps[w][lr * 40 + lg * 8]);
        bf16x8 af1 = *reinterpret_cast<const bf16x8*>(&ps[w][(16 + lr) * 40 + lg * 8]);
        #pragma unroll
        for (int dt = 0; dt < 16; ++dt) {
            bf16x8 vfr = *reinterpret_cast<const bf16x8*>(&Vls[cur][dt * 512 + l * 8]);
            oacc[0][dt] = __builtin_amdgcn_mfma_f32_16x16x32_bf16(af0, vfr, oacc[0][dt], 0, 0, 0);
            oacc[1][dt] = __builtin_amdgcn_mfma_f32_16x16x32_bf16(af1, vfr, oacc[1][dt], 0, 0, 0);
        }
        __syncthreads();
    }

    // epilogue: 4 commutative atomic contributions per element
    #pragma unroll
    for (int qs = 0; qs < 2; ++qs) {
        #pragma unroll
        for (int dt = 0; dt < 16; ++dt) {
            #pragma unroll
            for (int r = 0; r < 4; ++r) {
                int row = q0 + qs * 16 + lg * 4 + r;
                unsafeAtomicAdd(&out[((size_t)(b * S_LEN + row)) * D_DIM + dt * 16 + lr],
                                oacc[qs][dt][r]);
            }
        }
    }
    #undef STAGE_KV
}

// ---------------- launcher ------------------------------------------------
extern "C" void kernel_launch(void* const* d_in, const int* in_sizes, int n_in,
                              void* d_out, int out_size, void* d_ws, size_t ws_size,
                              hipStream_t stream) {
    const float* x  = (const float*)d_in[0];
    const float* Wq = (const float*)d_in[1];
    const float* bq = (const float*)d_in[2];
    const float* Wk = (const float*)d_in[3];
    const float* bk = (const float*)d_in[4];
    const float* Wv = (const float*)d_in[5];
    const float* bv = (const float*)d_in[6];
    float* out = (float*)d_out;

    u16* Qf = (u16*)d_ws;                              // 8 MB (fragment layout)
    u16* Kf = Qf + (size_t)NROW * D_DIM;               // 8 MB
    u16* Vf = Kf + (size_t)NROW * D_DIM;               // 8 MB
    u16* Wf = Vf + (size_t)NROW * D_DIM;               // 384 KB
    float* Zp = (float*)(Wf + 196608);                 // 256 KB (4 q-quarter partials)
    float* LZ = Zp + 4 * NROW;                         // 64 KB

    hipMemsetAsync(out, 0, (size_t)NROW * D_DIM * sizeof(float), stream);

    wconv<<<96, 256, 0, stream>>>(Wq, Wk, Wv, Wf);
    qkv_proj<<<NROW / 32, 256, 0, stream>>>(x, Wf, bq, bk, bv, Qf, Kf, Vf);
    col_denom<<<512, 256, 0, stream>>>(Qf, Kf, Zp);
    zlog<<<NROW / 256, 256, 0, stream>>>(Zp, LZ);
    attn_out<<<512, 256, 0, stream>>>(Qf, Kf, Vf, LZ, out);
}